// Round 1
// baseline (373.320 us; speedup 1.0000x reference)
//
#include <hip/hip_runtime.h>

// Problem constants (from reference):
// IRREPS = [(0,8),(1,8),(2,8),(3,8),(4,8)]  TOTAL_DIM=200  BATCH=2048  CHANNELS=128
// input (2048,200,128) f32; sincos_{alpha,beta,gamma} (2048,5,2) f32 [.,k,0]=sin(k*t) [.,k,1]=cos(k*t)
// out = per-irrep: Zalpha * A * Zbeta * A^T * Zgamma applied along the (2l+1) axis.

#define NBATCH 2048

// ---------- U-matrix row structure: row p of U(l) has <=2 entries value r * i^ph ----------
__device__ __forceinline__ int urow_entries(int L, int p, int* c, double* r, int* ph) {
  const double s2 = 0.70710678118654752440;  // 1/sqrt(2)
  int m = p - L;
  if (m == 0) { c[0] = L; r[0] = 1.0; ph[0] = 0; return 1; }
  if (m > 0) {
    c[0] = L + m; r[0] = ((m & 1) ? -s2 : s2); ph[0] = 0;   // (-1)^m/sqrt2
    c[1] = L - m; r[1] = s2;                  ph[1] = 0;    // 1/sqrt2
    return 2;
  }
  int mu = -m;
  c[0] = L - mu; r[0] = s2;                    ph[0] = 1;   // i/sqrt2
  c[1] = L + mu; r[1] = ((mu & 1) ? s2 : -s2); ph[1] = 1;   // -i*(-1)^mu/sqrt2
  return 2;
}

// ---------- build R_l(b) = Zalpha * A * Zbeta * A^T * Zgamma for one l ----------
template <int L>
__device__ __forceinline__ void build_R_impl(const float* __restrict__ sa,
                                             const float* __restrict__ sb,
                                             const float* __restrict__ sg,
                                             float* __restrict__ R_all,
                                             double* dsm, float* As,
                                             int blockX, int tid) {
  constexpr int D = 2 * L + 1;

  // Phase 1: small_d(L, beta=-pi/2) into LDS (double)
  if (tid < D * D) {
    int jp = tid / D, jm = tid % D;
    int mp = jp - L, m = jm - L;
    double f[9];
    f[0] = 1.0;
    for (int i = 1; i < 9; ++i) f[i] = f[i - 1] * (double)i;
    double pref = sqrt(f[L + mp] * f[L - mp] * f[L + m] * f[L - m]);
    const double c  =  0.70710678118654752440;   // cos(-pi/4)
    const double sn = -0.70710678118654752440;   // sin(-pi/4)
    double tot = 0.0;
    int s0 = (m - mp) > 0 ? (m - mp) : 0;
    int s1 = (L + m) < (L - mp) ? (L + m) : (L - mp);
    for (int s = s0; s <= s1; ++s) {
      double den  = f[L + m - s] * f[s] * f[mp - m + s] * f[L - mp - s];
      double term = (((mp - m + s) & 1) ? -1.0 : 1.0) / den;
      int e1 = 2 * L + m - mp - 2 * s;
      int e2 = mp - m + 2 * s;
      double p1 = 1.0, p2 = 1.0;
      for (int t = 0; t < e1; ++t) p1 *= c;
      for (int t = 0; t < e2; ++t) p2 *= sn;
      tot += term * p1 * p2;
    }
    dsm[tid] = pref * tot;
  }
  __syncthreads();

  // Phase 2: A = Re(U * Dc * U^H), Dc[j][k] = i^(j-k) * dsm[j][k]
  if (tid < D * D) {
    int p = tid / D, q = tid % D;
    int c1[2], ph1[2], c2[2], ph2[2];
    double r1[2], r2[2];
    int n1 = urow_entries(L, p, c1, r1, ph1);
    int n2 = urow_entries(L, q, c2, r2, ph2);
    double acc = 0.0;
    for (int a = 0; a < n1; ++a)
      for (int bq = 0; bq < n2; ++bq) {
        int tp = ((c1[a] - c2[bq]) + ph1[a] - ph2[bq] + 12) & 3;  // power of i, mod 4
        double v = r1[a] * r2[bq] * dsm[c1[a] * D + c2[bq]];
        if (tp == 0) acc += v;
        else if (tp == 2) acc -= v;
        // odd powers: purely imaginary -> no real contribution
      }
    As[tid] = (float)acc;
  }
  __syncthreads();

  // Phase 3: one thread per batch element; column-wise composition.
  // Zrot as matrix: Z[j][j] = cos(|j-L| t), Z[j][2L-j] = sign(j-L) sin(|j-L| t)
  int b = blockX * 256 + tid;
  float ca[D], sav[D], cb[D], sbv[D];
#pragma unroll
  for (int i = 0; i < D; ++i) {
    int mm = i - L;
    int am = mm < 0 ? -mm : mm;
    float sgn = (float)((mm > 0) - (mm < 0));
    ca[i] = sa[b * 10 + am * 2 + 1];
    sav[i] = sgn * sa[b * 10 + am * 2 + 0];
    cb[i] = sb[b * 10 + am * 2 + 1];
    sbv[i] = sgn * sb[b * 10 + am * 2 + 0];
  }
  constexpr int offR[5] = {0, 1, 10, 35, 84};
  float* Rout = R_all + (size_t)b * 165 + offR[L];
#pragma unroll
  for (int k = 0; k < D; ++k) {
    int mmk = k - L;
    int amk = mmk < 0 ? -mmk : mmk;
    float sgnk = (float)((mmk > 0) - (mmk < 0));
    float cgk = sg[b * 10 + amk * 2 + 1];
    float sgk = sgnk * sg[b * 10 + amk * 2 + 0];
    float c2v[D], c3v[D], c4v[D];
    // col k of (A^T * Zgamma):  c2[i] = cg_k*A[k][i] - sg_k*A[2L-k][i]
#pragma unroll
    for (int i = 0; i < D; ++i)
      c2v[i] = cgk * As[k * D + i] - sgk * As[(2 * L - k) * D + i];
    // col k of (Zbeta * ^):     c3[i] = cb_i*c2[i] + sb_i*c2[2L-i]
#pragma unroll
    for (int i = 0; i < D; ++i) c3v[i] = cb[i] * c2v[i] + sbv[i] * c2v[2 * L - i];
    // col k of (A * ^)
#pragma unroll
    for (int p = 0; p < D; ++p) {
      float s = 0.f;
#pragma unroll
      for (int i = 0; i < D; ++i) s = fmaf(As[p * D + i], c3v[i], s);
      c4v[p] = s;
    }
    // col k of (Zalpha * ^)
#pragma unroll
    for (int p = 0; p < D; ++p)
      Rout[p * D + k] = ca[p] * c4v[p] + sav[p] * c4v[2 * L - p];
  }
}

__global__ __launch_bounds__(256) void build_R_kernel(const float* __restrict__ sa,
                                                      const float* __restrict__ sb,
                                                      const float* __restrict__ sg,
                                                      float* __restrict__ R_all) {
  __shared__ double dsm[81];
  __shared__ float As[81];
  int tid = threadIdx.x;
  switch (blockIdx.y) {
    case 0: build_R_impl<0>(sa, sb, sg, R_all, dsm, As, blockIdx.x, tid); break;
    case 1: build_R_impl<1>(sa, sb, sg, R_all, dsm, As, blockIdx.x, tid); break;
    case 2: build_R_impl<2>(sa, sb, sg, R_all, dsm, As, blockIdx.x, tid); break;
    case 3: build_R_impl<3>(sa, sb, sg, R_all, dsm, As, blockIdx.x, tid); break;
    case 4: build_R_impl<4>(sa, sb, sg, R_all, dsm, As, blockIdx.x, tid); break;
  }
}

// ---------- main streaming pass: out[b, seg] = R_l(b) @ in[b, seg] over channels ----------
template <int L>
__device__ __forceinline__ void apply_seg(const float4* __restrict__ ip0,
                                          float4* __restrict__ op0,
                                          const float* __restrict__ Rl, int mBase) {
  constexpr int D = 2 * L + 1;
#pragma unroll
  for (int mi = 0; mi < 4; ++mi) {
    int m = mBase + mi;
    const float4* ip = ip0 + m * D * 32;
    float4* op = op0 + m * D * 32;
    float4 x[D];
#pragma unroll
    for (int j = 0; j < D; ++j) x[j] = ip[j * 32];
#pragma unroll
    for (int i = 0; i < D; ++i) {
      float r = Rl[i * D];
      float4 a;
      a.x = r * x[0].x; a.y = r * x[0].y; a.z = r * x[0].z; a.w = r * x[0].w;
#pragma unroll
      for (int j = 1; j < D; ++j) {
        r = Rl[i * D + j];
        a.x = fmaf(r, x[j].x, a.x);
        a.y = fmaf(r, x[j].y, a.y);
        a.z = fmaf(r, x[j].z, a.z);
        a.w = fmaf(r, x[j].w, a.w);
      }
      op[i * 32] = a;
    }
  }
}

__global__ __launch_bounds__(256) void apply_R_kernel(const float* __restrict__ in,
                                                      const float* __restrict__ R_all,
                                                      float* __restrict__ out) {
  __shared__ float Rs[8][165];
  int tid = threadIdx.x;
  int g = tid >> 5;        // which batch element in this block (0..7)
  int q = tid & 31;        // float4 channel-quad index (128 channels / 4)
  int b = blockIdx.x * 8 + g;
  for (int t = q; t < 165; t += 32) Rs[g][t] = R_all[(size_t)b * 165 + t];
  __syncthreads();
  int mBase = blockIdx.y * 4;  // mults 0..3 or 4..7
  const float4* ib = (const float4*)in + (size_t)b * 6400 + q;  // 200 rows * 32 quads
  float4* ob = (float4*)out + (size_t)b * 6400 + q;
  const float* Rg = Rs[g];
  // row bases: l=0:0, l=1:8, l=2:32, l=3:72, l=4:128 ; R offsets {0,1,10,35,84}
  apply_seg<0>(ib + 0 * 32,   ob + 0 * 32,   Rg + 0,  mBase);
  apply_seg<1>(ib + 8 * 32,   ob + 8 * 32,   Rg + 1,  mBase);
  apply_seg<2>(ib + 32 * 32,  ob + 32 * 32,  Rg + 10, mBase);
  apply_seg<3>(ib + 72 * 32,  ob + 72 * 32,  Rg + 35, mBase);
  apply_seg<4>(ib + 128 * 32, ob + 128 * 32, Rg + 84, mBase);
}

extern "C" void kernel_launch(void* const* d_in, const int* in_sizes, int n_in,
                              void* d_out, int out_size, void* d_ws, size_t ws_size,
                              hipStream_t stream) {
  const float* in = (const float*)d_in[0];
  const float* sa = (const float*)d_in[1];
  const float* sb = (const float*)d_in[2];
  const float* sg = (const float*)d_in[3];
  float* out = (float*)d_out;
  float* R_all = (float*)d_ws;  // 2048 * 165 floats = 1.35 MB

  build_R_kernel<<<dim3(8, 5), 256, 0, stream>>>(sa, sb, sg, R_all);
  apply_R_kernel<<<dim3(NBATCH / 8, 2), 256, 0, stream>>>(in, R_all, out);
}

// Round 2
// 358.022 us; speedup vs baseline: 1.0427x; 1.0427x over previous
//
#include <hip/hip_runtime.h>

// IRREPS = [(0,8),(1,8),(2,8),(3,8),(4,8)]  TOTAL_DIM=200  BATCH=2048  CHANNELS=128
// input (2048,200,128) f32; sincos_* (2048,5,2) f32, [b,m,0]=sin(m*t), [b,m,1]=cos(m*t)
// out per irrep l: R_l(b) = Zalpha * A_l * Zbeta * A_l^T * Zgamma applied along the (2l+1) axis.
//
// Fused single kernel: one block per batch element.
//   Prologue (165 threads): small-d (f64) -> A (f64->f32) -> M = A Zb A^T -> R = Za M Zg, all in LDS.
//   Main: 8 groups of 32 lanes; group g = mult g, lane q = float4 channel-quad; stream 25 rows/group.

#define NBATCH 2048

// ---------- small-d element, beta = -pi/2 ----------
__device__ __forceinline__ double small_d_elem(int L, int jp, int jm) {
  int mp = jp - L, m = jm - L;
  double f[10];
  f[0] = 1.0;
  for (int i = 1; i < 10; ++i) f[i] = f[i - 1] * (double)i;
  double pref = sqrt(f[L + mp] * f[L - mp] * f[L + m] * f[L - m]);
  const double c  =  0.70710678118654752440;   // cos(-pi/4)
  const double sn = -0.70710678118654752440;   // sin(-pi/4)
  double tot = 0.0;
  int s0 = (m - mp) > 0 ? (m - mp) : 0;
  int s1 = (L + m) < (L - mp) ? (L + m) : (L - mp);
  for (int s = s0; s <= s1; ++s) {
    double den  = f[L + m - s] * f[s] * f[mp - m + s] * f[L - mp - s];
    double term = (((mp - m + s) & 1) ? -1.0 : 1.0) / den;
    int e1 = 2 * L + m - mp - 2 * s;
    int e2 = mp - m + 2 * s;
    double p1 = 1.0, p2 = 1.0;
    for (int t = 0; t < e1; ++t) p1 *= c;
    for (int t = 0; t < e2; ++t) p2 *= sn;
    tot += term * p1 * p2;
  }
  return pref * tot;
}

// ---------- row p of U(l): <=2 entries, value r * i^ph ----------
__device__ __forceinline__ int urow_entries(int L, int p, int* c, double* r, int* ph) {
  const double s2 = 0.70710678118654752440;  // 1/sqrt(2)
  int m = p - L;
  if (m == 0) { c[0] = L; r[0] = 1.0; ph[0] = 0; return 1; }
  if (m > 0) {
    c[0] = L + m; r[0] = ((m & 1) ? -s2 : s2); ph[0] = 0;
    c[1] = L - m; r[1] = s2;                   ph[1] = 0;
    return 2;
  }
  int mu = -m;
  c[0] = L - mu; r[0] = s2;                    ph[0] = 1;
  c[1] = L + mu; r[1] = ((mu & 1) ? s2 : -s2); ph[1] = 1;
  return 2;
}

// ---------- streaming apply for one irrep, one mult ----------
template <int L, int RB, int RO>
__device__ __forceinline__ void apply_block(const float4* __restrict__ ib,
                                            float4* __restrict__ ob,
                                            const float* __restrict__ Rsm, int g) {
  constexpr int D = 2 * L + 1;
  const float4* ip = ib + (RB + g * D) * 32;
  float4* op = ob + (RB + g * D) * 32;
  const float* R = Rsm + RO;
  float4 x[D];
#pragma unroll
  for (int j = 0; j < D; ++j) x[j] = ip[j * 32];
#pragma unroll
  for (int i = 0; i < D; ++i) {
    float r = R[i * D];
    float4 a;
    a.x = r * x[0].x; a.y = r * x[0].y; a.z = r * x[0].z; a.w = r * x[0].w;
#pragma unroll
    for (int j = 1; j < D; ++j) {
      r = R[i * D + j];
      a.x = fmaf(r, x[j].x, a.x);
      a.y = fmaf(r, x[j].y, a.y);
      a.z = fmaf(r, x[j].z, a.z);
      a.w = fmaf(r, x[j].w, a.w);
    }
    op[i * 32] = a;
  }
}

__global__ __launch_bounds__(256, 4) void wigner_fused_kernel(
    const float* __restrict__ in, const float* __restrict__ sa,
    const float* __restrict__ sb, const float* __restrict__ sg,
    float* __restrict__ out) {
  __shared__ double dsm[165];
  __shared__ float Asm[165];
  __shared__ float Msm[165];
  __shared__ float Rsm[165];

  const int t = threadIdx.x;
  const int b = blockIdx.x;

  // map thread -> (L, off, i, j) within the concatenated 165-element layout
  int L = 0, off = 0;
  if (t >= 84) { L = 4; off = 84; }
  else if (t >= 35) { L = 3; off = 35; }
  else if (t >= 10) { L = 2; off = 10; }
  else if (t >= 1)  { L = 1; off = 1; }
  const int D = 2 * L + 1;
  const int loc = t - off;
  const int i = loc / D;
  const int j = loc - i * D;

  // Phase 1: small-d into LDS (f64)
  if (t < 165) dsm[t] = small_d_elem(L, i, j);
  __syncthreads();

  // Phase 2: A[i][j] = Re( (U Dc U^H)[i][j] ), Dc[p][q] = i^(p-q) * dsm[p][q]
  if (t < 165) {
    int c1[2], ph1[2], c2[2], ph2[2];
    double r1[2], r2[2];
    int n1 = urow_entries(L, i, c1, r1, ph1);
    int n2 = urow_entries(L, j, c2, r2, ph2);
    double acc = 0.0;
    for (int a = 0; a < n1; ++a)
      for (int bq = 0; bq < n2; ++bq) {
        int tp = ((c1[a] - c2[bq]) + ph1[a] - ph2[bq] + 12) & 3;
        double v = r1[a] * r2[bq] * dsm[off + c1[a] * D + c2[bq]];
        if (tp == 0) acc += v;
        else if (tp == 2) acc -= v;
      }
    Asm[t] = (float)acc;
  }
  __syncthreads();

  // Phase 3: M[i][j] = sum_ii A[i][ii] * (cb_ii * A[j][ii] + sbv_ii * A[j][2L-ii])
  if (t < 165) {
    float acc = 0.0f;
    for (int ii = 0; ii < D; ++ii) {
      int mm = ii - L;
      int am = mm < 0 ? -mm : mm;
      float sgn = (float)((mm > 0) - (mm < 0));
      float cb = sb[b * 10 + am * 2 + 1];
      float sv = sgn * sb[b * 10 + am * 2 + 0];
      acc += Asm[off + i * D + ii] *
             (cb * Asm[off + j * D + ii] + sv * Asm[off + j * D + (2 * L - ii)]);
    }
    Msm[t] = acc;
  }
  __syncthreads();

  // Phase 4: R[p][k] = ca_p*(cg_k*M[p][k] - sgv_k*M[p][2L-k])
  //                  + sav_p*(cg_k*M[2L-p][k] - sgv_k*M[2L-p][2L-k])
  if (t < 165) {
    int p = i, k = j;
    int mmp = p - L, amp = mmp < 0 ? -mmp : mmp;
    float sgp = (float)((mmp > 0) - (mmp < 0));
    float cap = sa[b * 10 + amp * 2 + 1];
    float sav = sgp * sa[b * 10 + amp * 2 + 0];
    int mmk = k - L, amk = mmk < 0 ? -mmk : mmk;
    float sgk = (float)((mmk > 0) - (mmk < 0));
    float cgk = sg[b * 10 + amk * 2 + 1];
    float sgv = sgk * sg[b * 10 + amk * 2 + 0];
    float m00 = Msm[off + p * D + k];
    float m01 = Msm[off + p * D + (2 * L - k)];
    float m10 = Msm[off + (2 * L - p) * D + k];
    float m11 = Msm[off + (2 * L - p) * D + (2 * L - k)];
    Rsm[t] = cap * (cgk * m00 - sgv * m01) + sav * (cgk * m10 - sgv * m11);
  }
  __syncthreads();

  // Main streaming pass: group g (tid>>5) = mult g; lane q = channel quad.
  const int g = t >> 5;
  const int q = t & 31;
  const float4* ib = (const float4*)in + (size_t)b * 6400 + q;  // 200 rows * 32 quads
  float4* ob = (float4*)out + (size_t)b * 6400 + q;
  // row bases (per-irrep block start, rows): l=0:0, l=1:8, l=2:32, l=3:72, l=4:128
  // R offsets (cumulative D^2): {0,1,10,35,84}
  apply_block<0, 0,   0 >(ib, ob, Rsm, g);
  apply_block<1, 8,   1 >(ib, ob, Rsm, g);
  apply_block<2, 32,  10>(ib, ob, Rsm, g);
  apply_block<3, 72,  35>(ib, ob, Rsm, g);
  apply_block<4, 128, 84>(ib, ob, Rsm, g);
}

extern "C" void kernel_launch(void* const* d_in, const int* in_sizes, int n_in,
                              void* d_out, int out_size, void* d_ws, size_t ws_size,
                              hipStream_t stream) {
  const float* in = (const float*)d_in[0];
  const float* sa = (const float*)d_in[1];
  const float* sb = (const float*)d_in[2];
  const float* sg = (const float*)d_in[3];
  float* out = (float*)d_out;

  wigner_fused_kernel<<<dim3(NBATCH), 256, 0, stream>>>(in, sa, sb, sg, out);
}

// Round 3
// 353.832 us; speedup vs baseline: 1.0551x; 1.0118x over previous
//
#include <hip/hip_runtime.h>
#include <math.h>

// IRREPS = [(0,8),(1,8),(2,8),(3,8),(4,8)]  TOTAL_DIM=200  BATCH=2048  CHANNELS=128
// input (2048,200,128) f32; sincos_* (2048,5,2) f32, [b,m,0]=sin(m*t), [b,m,1]=cos(m*t)
// out per irrep l: R_l(b) = Zalpha * A_l * Zbeta * A_l^T * Zgamma along the (2l+1) axis.
//
// R3: A_l computed on HOST (f64) once per launch, passed by value as the FIRST kernel
// arg (kernarg offset 0) and read in-kernel via the kernarg segment pointer (LDS copy).
// Per-block prologue is now: A->LDS, M = A Zb A^T, R = Za M Zg (3 barriers, no f64).
// l=0/l=1 input rows are prefetched into registers before the prologue barriers.

#define NBATCH 2048

// ---------- shared host/device helpers ----------
__host__ __device__ __forceinline__ double small_d_elem_hd(int L, int jp, int jm) {
  int mp = jp - L, m = jm - L;
  double f[10];
  f[0] = 1.0;
  for (int i = 1; i < 10; ++i) f[i] = f[i - 1] * (double)i;
  double pref = sqrt(f[L + mp] * f[L - mp] * f[L + m] * f[L - m]);
  const double c  =  0.70710678118654752440;   // cos(-pi/4)
  const double sn = -0.70710678118654752440;   // sin(-pi/4)
  double tot = 0.0;
  int s0 = (m - mp) > 0 ? (m - mp) : 0;
  int s1 = (L + m) < (L - mp) ? (L + m) : (L - mp);
  for (int s = s0; s <= s1; ++s) {
    double den  = f[L + m - s] * f[s] * f[mp - m + s] * f[L - mp - s];
    double term = (((mp - m + s) & 1) ? -1.0 : 1.0) / den;
    int e1 = 2 * L + m - mp - 2 * s;
    int e2 = mp - m + 2 * s;
    double p1 = 1.0, p2 = 1.0;
    for (int t = 0; t < e1; ++t) p1 *= c;
    for (int t = 0; t < e2; ++t) p2 *= sn;
    tot += term * p1 * p2;
  }
  return pref * tot;
}

__host__ __device__ __forceinline__ int urow_entries_hd(int L, int p, int* c, double* r, int* ph) {
  const double s2 = 0.70710678118654752440;  // 1/sqrt(2)
  int m = p - L;
  if (m == 0) { c[0] = L; r[0] = 1.0; ph[0] = 0; return 1; }
  if (m > 0) {
    c[0] = L + m; r[0] = ((m & 1) ? -s2 : s2); ph[0] = 0;
    c[1] = L - m; r[1] = s2;                   ph[1] = 0;
    return 2;
  }
  int mu = -m;
  c[0] = L - mu; r[0] = s2;                    ph[0] = 1;
  c[1] = L + mu; r[1] = ((mu & 1) ? s2 : -s2); ph[1] = 1;
  return 2;
}

// ---------- host: build all A_l, concatenated {1,9,25,49,81} = 165 floats ----------
struct APack { float a[165]; };

static void host_compute_A(APack* out) {
  const int offs[5] = {0, 1, 10, 35, 84};
  for (int L = 0; L <= 4; ++L) {
    const int D = 2 * L + 1;
    double dsm[81];
    for (int jp = 0; jp < D; ++jp)
      for (int jm = 0; jm < D; ++jm)
        dsm[jp * D + jm] = small_d_elem_hd(L, jp, jm);
    for (int p = 0; p < D; ++p)
      for (int q = 0; q < D; ++q) {
        int c1[2], ph1[2], c2[2], ph2[2];
        double r1[2], r2[2];
        int n1 = urow_entries_hd(L, p, c1, r1, ph1);
        int n2 = urow_entries_hd(L, q, c2, r2, ph2);
        double acc = 0.0;
        for (int a = 0; a < n1; ++a)
          for (int bq = 0; bq < n2; ++bq) {
            int tp = ((c1[a] - c2[bq]) + ph1[a] - ph2[bq] + 12) & 3;  // power of i mod 4
            double v = r1[a] * r2[bq] * dsm[c1[a] * D + c2[bq]];
            if (tp == 0) acc += v;
            else if (tp == 2) acc -= v;
          }
        out->a[offs[L] + p * D + q] = (float)acc;
      }
  }
}

// ---------- streaming apply for one irrep (rows RB + g*D .. ), R at Rsm+RO ----------
template <int L, int RB, int RO>
__device__ __forceinline__ void apply_block(const float4* __restrict__ ib,
                                            float4* __restrict__ ob,
                                            const float* __restrict__ Rsm, int g) {
  constexpr int D = 2 * L + 1;
  const float4* ip = ib + (RB + g * D) * 32;
  float4* op = ob + (RB + g * D) * 32;
  const float* R = Rsm + RO;
  float4 x[D];
#pragma unroll
  for (int j = 0; j < D; ++j) x[j] = ip[j * 32];
#pragma unroll
  for (int i = 0; i < D; ++i) {
    float r = R[i * D];
    float4 a;
    a.x = r * x[0].x; a.y = r * x[0].y; a.z = r * x[0].z; a.w = r * x[0].w;
#pragma unroll
    for (int j = 1; j < D; ++j) {
      r = R[i * D + j];
      a.x = fmaf(r, x[j].x, a.x);
      a.y = fmaf(r, x[j].y, a.y);
      a.z = fmaf(r, x[j].z, a.z);
      a.w = fmaf(r, x[j].w, a.w);
    }
    op[i * 32] = a;
  }
}

__global__ __launch_bounds__(256, 4) void wigner_fused2(
    APack Ap,  // MUST be first arg: read via kernarg segment at offset 0
    const float* __restrict__ in, const float* __restrict__ sa,
    const float* __restrict__ sb, const float* __restrict__ sg,
    float* __restrict__ out) {
  (void)Ap;
  __shared__ float Asm[165];
  __shared__ float Msm[165];
  __shared__ float Rsm[165];

  const int t = threadIdx.x;
  const int b = blockIdx.x;
  const int g = t >> 5;   // mult 0..7
  const int q = t & 31;   // float4 channel-quad

  const float4* ib = (const float4*)in + (size_t)b * 6400 + q;  // 200 rows * 32 quads
  float4* ob = (float4*)out + (size_t)b * 6400 + q;

  // Prefetch l=0 (row g) and l=1 (rows 8+g*3+j) while the prologue runs.
  float4 p0 = ib[g * 32];
  float4 p1[3];
#pragma unroll
  for (int j = 0; j < 3; ++j) p1[j] = ib[(8 + g * 3 + j) * 32];

  // A from kernarg segment (offset 0) -> LDS. Avoids byval scratch spill.
  const float* Ak = (const float*)__builtin_amdgcn_kernarg_segment_ptr();
  if (t < 165) Asm[t] = Ak[t];

  // thread -> (L, off, i, j) in concatenated 165 layout
  int L = 0, off = 0;
  if (t >= 84) { L = 4; off = 84; }
  else if (t >= 35) { L = 3; off = 35; }
  else if (t >= 10) { L = 2; off = 10; }
  else if (t >= 1)  { L = 1; off = 1; }
  const int D = 2 * L + 1;
  const int loc = t - off;
  const int i = loc / D;
  const int j = loc - i * D;
  __syncthreads();

  // M[i][j] = sum_ii A[i][ii] * (cb_ii * A[j][ii] + sbv_ii * A[j][2L-ii])
  if (t < 165) {
    float acc = 0.0f;
    for (int ii = 0; ii < D; ++ii) {
      int mm = ii - L;
      int am = mm < 0 ? -mm : mm;
      float sgn = (float)((mm > 0) - (mm < 0));
      float cb = sb[b * 10 + am * 2 + 1];
      float sv = sgn * sb[b * 10 + am * 2 + 0];
      acc += Asm[off + i * D + ii] *
             (cb * Asm[off + j * D + ii] + sv * Asm[off + j * D + (2 * L - ii)]);
    }
    Msm[t] = acc;
  }
  __syncthreads();

  // R[p][k] = ca_p*(cg_k*M[p][k] - sgv_k*M[p][2L-k]) + sav_p*(cg_k*M[2L-p][k] - sgv_k*M[2L-p][2L-k])
  if (t < 165) {
    int p = i, k = j;
    int mmp = p - L, amp = mmp < 0 ? -mmp : mmp;
    float sgp = (float)((mmp > 0) - (mmp < 0));
    float cap = sa[b * 10 + amp * 2 + 1];
    float sav = sgp * sa[b * 10 + amp * 2 + 0];
    int mmk = k - L, amk = mmk < 0 ? -mmk : mmk;
    float sgk = (float)((mmk > 0) - (mmk < 0));
    float cgk = sg[b * 10 + amk * 2 + 1];
    float sgv = sgk * sg[b * 10 + amk * 2 + 0];
    float m00 = Msm[off + p * D + k];
    float m01 = Msm[off + p * D + (2 * L - k)];
    float m10 = Msm[off + (2 * L - p) * D + k];
    float m11 = Msm[off + (2 * L - p) * D + (2 * L - k)];
    Rsm[t] = cap * (cgk * m00 - sgv * m01) + sav * (cgk * m10 - sgv * m11);
  }
  __syncthreads();

  // l=0 from prefetched register
  {
    float r0 = Rsm[0];
    float4 a;
    a.x = r0 * p0.x; a.y = r0 * p0.y; a.z = r0 * p0.z; a.w = r0 * p0.w;
    ob[g * 32] = a;
  }
  // l=1 (3x3) from prefetched registers, R at Rsm+1
  {
    const float* R1 = Rsm + 1;
#pragma unroll
    for (int i2 = 0; i2 < 3; ++i2) {
      float r = R1[i2 * 3];
      float4 a;
      a.x = r * p1[0].x; a.y = r * p1[0].y; a.z = r * p1[0].z; a.w = r * p1[0].w;
#pragma unroll
      for (int j2 = 1; j2 < 3; ++j2) {
        r = R1[i2 * 3 + j2];
        a.x = fmaf(r, p1[j2].x, a.x);
        a.y = fmaf(r, p1[j2].y, a.y);
        a.z = fmaf(r, p1[j2].z, a.z);
        a.w = fmaf(r, p1[j2].w, a.w);
      }
      ob[(8 + g * 3 + i2) * 32] = a;
    }
  }
  // l=2,3,4 streamed
  apply_block<2, 32,  10>(ib, ob, Rsm, g);
  apply_block<3, 72,  35>(ib, ob, Rsm, g);
  apply_block<4, 128, 84>(ib, ob, Rsm, g);
}

extern "C" void kernel_launch(void* const* d_in, const int* in_sizes, int n_in,
                              void* d_out, int out_size, void* d_ws, size_t ws_size,
                              hipStream_t stream) {
  const float* in = (const float*)d_in[0];
  const float* sa = (const float*)d_in[1];
  const float* sb = (const float*)d_in[2];
  const float* sg = (const float*)d_in[3];
  float* out = (float*)d_out;

  APack Ap;
  host_compute_A(&Ap);

  wigner_fused2<<<dim3(NBATCH), 256, 0, stream>>>(Ap, in, sa, sb, sg, out);
}